// Round 10
// baseline (277.951 us; speedup 1.0000x reference)
//
#include <hip/hip_runtime.h>
#include <stdint.h>

#define B_DIM 4
#define L_DIM 512
#define D_DIM 768
#define S_DIM 4096
#define DFF_DIM 3072
#define M_DIM (B_DIM * S_DIM)   // 16384

typedef unsigned short ushort_t;
typedef __attribute__((ext_vector_type(8))) short short8;
typedef __attribute__((ext_vector_type(4))) short short4v;
typedef __attribute__((ext_vector_type(4))) float floatx4;

// round-to-nearest-even fp32 -> bf16 bits
__device__ __forceinline__ ushort_t f2bf(float x) {
  unsigned int u = __float_as_uint(x);
  u += 0x7FFFu + ((u >> 16) & 1u);
  return (ushort_t)(u >> 16);
}

// async 16B global->LDS (lane-contiguous dest)
__device__ __forceinline__ void load_lds16(const ushort_t* g, ushort_t* lds) {
  __builtin_amdgcn_global_load_lds(
      (const __attribute__((address_space(1))) unsigned int*)g,
      (__attribute__((address_space(3))) unsigned int*)lds, 16, 0, 0);
}

// single-barrier phase fence (no memory clobber -> no compiler vmcnt drain)
#define PIN() __builtin_amdgcn_sched_barrier(0)
#define BAR()                                  \
  do {                                         \
    PIN();                                     \
    __builtin_amdgcn_s_barrier();              \
    PIN();                                     \
  } while (0)
#define WAIT_LGKM0()                           \
  do {                                         \
    asm volatile("s_waitcnt lgkmcnt(0)");      \
    PIN();                                     \
  } while (0)
#define WAIT_VM(n)                             \
  do {                                         \
    asm volatile("s_waitcnt vmcnt(" #n ")");   \
    PIN();                                     \
  } while (0)

// ---------------------------------------------------------------------------
// prep: W1 transpose (2304 blocks) + span gather (4096 blocks).
// W2 transpose moved into the gemm1 launch (fills gemm1's CU-drain tail).
// ---------------------------------------------------------------------------
__device__ __forceinline__ void transpose_body(const float* __restrict__ in,
                                               ushort_t* __restrict__ out,
                                               int K, int N, int kb, int nb) {
  __shared__ float tile[32][33];
  const int k0 = kb * 32;
  const int n0 = nb * 32;
  const int tx = threadIdx.x & 31;
  const int ty = threadIdx.x >> 5;  // 0..7
#pragma unroll
  for (int r = 0; r < 32; r += 8)
    tile[ty + r][tx] = in[(long)(k0 + ty + r) * N + n0 + tx];
  __syncthreads();
#pragma unroll
  for (int r = 0; r < 32; r += 8)
    out[(long)(n0 + ty + r) * K + k0 + tx] = f2bf(tile[tx][ty + r]);
}

__device__ __forceinline__ void span_body(const float* __restrict__ h,
                                          const int* __restrict__ span_idx,
                                          ushort_t* __restrict__ A, int blk) {
  const int wave = threadIdx.x >> 6;
  const int lane = threadIdx.x & 63;
  const int span = blk * 4 + wave;  // 0..M-1
  const int b = span >> 12;
  const int start = span_idx[span * 2 + 0];
  const int end   = span_idx[span * 2 + 1];
  const float inv = 1.0f / (float)(end - start + 1);
  const floatx4* hb = (const floatx4*)(h + (long)b * L_DIM * D_DIM) + lane;
  floatx4 a[3];
#pragma unroll
  for (int c = 0; c < 3; ++c) a[c] = (floatx4)0.0f;
  for (int p = start; p <= end; p += 2) {
    const int p1 = (p + 1 <= end) ? p + 1 : p;       // clamped (in-bounds)
    const float m1 = (p + 1 <= end) ? 1.0f : 0.0f;   // mask for second row
    const floatx4* h0 = hb + (long)p * 192;
    const floatx4* h1 = hb + (long)p1 * 192;
    floatx4 v0[3], v1[3];
#pragma unroll
    for (int c = 0; c < 3; ++c) v0[c] = h0[c * 64];
#pragma unroll
    for (int c = 0; c < 3; ++c) v1[c] = h1[c * 64];
#pragma unroll
    for (int c = 0; c < 3; ++c) {
      a[c] += v0[c];
#pragma unroll
      for (int e = 0; e < 4; ++e) a[c][e] += m1 * v1[c][e];  // fma, masked
    }
  }
  short4v* o = (short4v*)(A + (long)span * D_DIM) + lane;
#pragma unroll
  for (int c = 0; c < 3; ++c) {
    short4v s;
#pragma unroll
    for (int e = 0; e < 4; ++e) s[e] = (short)f2bf(a[c][e] * inv);
    o[c * 64] = s;
  }
}

__global__ __launch_bounds__(256)
void prep(const float* __restrict__ W1, ushort_t* __restrict__ W1T,
          const float* __restrict__ h, const int* __restrict__ span_idx,
          ushort_t* __restrict__ A) {
  const int blk = blockIdx.x;
  if (blk < 2304) {
    transpose_body(W1, W1T, D_DIM, DFF_DIM, blk % 24, blk / 24);
  } else {
    span_body(h, span_idx, A, blk - 2304);
  }
}

// ---------------------------------------------------------------------------
// GEMM1 (R5-proven K-loop, 102-105 us): single-barrier, triple-buffered,
// 128x256 BK=64. 1-D grid 1824 blocks:
//   blk <  1536 : GEMM tile (bm = blk&127 fast, bn = blk>>7)
//   blk >= 1536 : W2 transpose, 8 tiles/block (2 halves x 4) -- consumed only
//                 by the NEXT kernel (GEMM2); packs into gemm1's drain tail.
// Epilogue: j-innermost store order (4 x 32B segments of one 64B line are
// temporally adjacent -> L2 write combining; WRITE_SIZE was 137MB vs 100 ideal).
// ---------------------------------------------------------------------------
__global__ __launch_bounds__(512, 2)
void gemm1_p3(const ushort_t* __restrict__ A, const ushort_t* __restrict__ Bt,
              const float* __restrict__ bias, ushort_t* __restrict__ C,
              const float* __restrict__ W2, ushort_t* __restrict__ W2T) {
  __shared__ ushort_t As[3][128 * 64];  // 49152 B
  __shared__ ushort_t Bs[3][256 * 64];  // 98304 B

  const int tid = threadIdx.x;
  const int blk = blockIdx.x;

  if (blk >= 1536) {
    // ---- fused W2 transpose: [3072][768] fp32 -> W2T [768][3072] bf16 ----
    const int half = tid >> 8;       // 0..1 (two 256-thread groups)
    const int ttid = tid & 255;
    const int tx = ttid & 31, ty = ttid >> 5;
    float* scratch = (float*)&As[0][0] + half * (32 * 33);
#pragma unroll
    for (int it = 0; it < 4; ++it) {
      const int tile = (blk - 1536) * 8 + half * 4 + it;  // 0..2303
      const int kb = tile % 96, nb = tile / 96;
      const int k0 = kb * 32, n0 = nb * 32;
#pragma unroll
      for (int r = 0; r < 32; r += 8)
        scratch[(ty + r) * 33 + tx] = W2[(long)(k0 + ty + r) * 768 + n0 + tx];
      __syncthreads();
#pragma unroll
      for (int r = 0; r < 32; r += 8)
        W2T[(long)(n0 + ty + r) * 3072 + k0 + tx] = f2bf(scratch[tx * 33 + ty + r]);
      __syncthreads();  // WAR: scratch reused next iteration
    }
    return;
  }

  const int lane = tid & 63;
  const int l16  = lane & 15;
  const int quad = lane >> 4;
  const int wave = tid >> 6;
  const int wr   = wave >> 2;  // 0..1 (M half, 64 rows)
  const int wc   = wave & 3;   // 0..3 (N quarter, 64 cols)

  const int bm = blk & 127;    // fast index (same order as dim3(128,12))
  const int bn = blk >> 7;     // 0..11

  // staging: seg s -> LDS row s>>3, slot s&7; global chunk = slot ^ (row&7)
  const int srow = tid >> 3;   // 0..63
  const int gch  = (tid & 7) ^ (srow & 7);
  const ushort_t* gA = A  + (long)(bm * 128 + srow) * 768 + gch * 8;
  const ushort_t* gB = Bt + (long)(bn * 256 + srow) * 768 + gch * 8;
  const long r64 = (long)768 * 64;  // 64-row stride (XOR pattern repeats mod 8)

  auto STAGE_A = [&](int buf, int kt) {   // A rows 0..127 (2 loads)
    const long ko = (long)kt * 64;
    ushort_t* la = &As[buf][0] + tid * 8;
    load_lds16(gA + ko,       la);
    load_lds16(gA + ko + r64, la + 4096);
  };
  auto STAGE_B01 = [&](int buf, int kt) { // B rows 0..127
    const long ko = (long)kt * 64;
    ushort_t* lb = &Bs[buf][0] + tid * 8;
    load_lds16(gB + ko,       lb);
    load_lds16(gB + ko + r64, lb + 4096);
  };
  auto STAGE_B23 = [&](int buf, int kt) { // B rows 128..255
    const long ko = (long)kt * 64;
    ushort_t* lb = &Bs[buf][0] + tid * 8;
    load_lds16(gB + ko + 2 * r64, lb + 8192);
    load_lds16(gB + ko + 3 * r64, lb + 12288);
  };

  // fragment reads: elem = row*64 + (kchunk ^ (row&7))*8 ; row&7 == l16&7
  const int arow0 = (wr * 64 + l16) * 64;
  const int brow0 = (wc * 64 + l16) * 64;
  const int cx0 = ((quad)     ^ (l16 & 7)) << 3;  // kstep 0
  const int cx1 = ((quad + 4) ^ (l16 & 7)) << 3;  // kstep 1

  floatx4 acc[4][4];
#pragma unroll
  for (int i = 0; i < 4; ++i)
#pragma unroll
    for (int j = 0; j < 4; ++j) acc[i][j] = (floatx4)0.0f;

  const int nk = 12;  // 768 / 64

  // prologue: stage tiles 0 and 1; gate tile 0 (tile 1's 6 stay in flight)
  STAGE_A(0, 0); STAGE_B01(0, 0); STAGE_B23(0, 0);
  STAGE_A(1, 1); STAGE_B01(1, 1); STAGE_B23(1, 1);
  WAIT_VM(6);
  BAR();

  short8 a0[2][2], a2[2][2], b0[2][2], b2[2][2];  // [frag][kstep]
  int cur = 0;

  for (int k = 0; k < nk; ++k) {
    const int s2 = (cur + 2 >= 3) ? cur - 1 : cur + 2;  // (k+2)%3
    const ushort_t* Ac = &As[cur][0];
    const ushort_t* Bc = &Bs[cur][0];
    const bool pf = (k + 2 < nk);

    // ---- Ph0: ds a0(i=0,1) + b0(j=0,1); stage A(k+2) | MFMA q00 ----------
#pragma unroll
    for (int i = 0; i < 2; ++i) {
      a0[i][0] = *(const short8*)(Ac + arow0 + i * 1024 + cx0);
      a0[i][1] = *(const short8*)(Ac + arow0 + i * 1024 + cx1);
    }
#pragma unroll
    for (int j = 0; j < 2; ++j) {
      b0[j][0] = *(const short8*)(Bc + brow0 + j * 1024 + cx0);
      b0[j][1] = *(const short8*)(Bc + brow0 + j * 1024 + cx1);
    }
    if (pf) STAGE_A(s2, k + 2);
    BAR();
    WAIT_LGKM0();
    __builtin_amdgcn_s_setprio(1);
#pragma unroll
    for (int i = 0; i < 2; ++i)
#pragma unroll
      for (int j = 0; j < 2; ++j) {
        acc[i][j] = __builtin_amdgcn_mfma_f32_16x16x32_bf16(a0[i][0], b0[j][0], acc[i][j], 0, 0, 0);
        acc[i][j] = __builtin_amdgcn_mfma_f32_16x16x32_bf16(a0[i][1], b0[j][1], acc[i][j], 0, 0, 0);
      }
    __builtin_amdgcn_s_setprio(0);

    // ---- Ph1: ds b2(j=2,3); stage B01(k+2) | MFMA q01 ---------------------
#pragma unroll
    for (int j = 0; j < 2; ++j) {
      b2[j][0] = *(const short8*)(Bc + brow0 + (2 + j) * 1024 + cx0);
      b2[j][1] = *(const short8*)(Bc + brow0 + (2 + j) * 1024 + cx1);
    }
    if (pf) STAGE_B01(s2, k + 2);
    BAR();
    WAIT_LGKM0();
    __builtin_amdgcn_s_setprio(1);
#pragma unroll
    for (int i = 0; i < 2; ++i)
#pragma unroll
      for (int j = 0; j < 2; ++j) {
        acc[i][2 + j] = __builtin_amdgcn_mfma_f32_16x16x32_bf16(a0[i][0], b2[j][0], acc[i][2 + j], 0, 0, 0);
        acc[i][2 + j] = __builtin_amdgcn_mfma_f32_16x16x32_bf16(a0[i][1], b2[j][1], acc[i][2 + j], 0, 0, 0);
      }
    __builtin_amdgcn_s_setprio(0);

    // ---- Ph2: ds a2(i=2,3); stage B23(k+2) | MFMA q11 ---------------------
#pragma unroll
    for (int i = 0; i < 2; ++i) {
      a2[i][0] = *(const short8*)(Ac + arow0 + (2 + i) * 1024 + cx0);
      a2[i][1] = *(const short8*)(Ac + arow0 + (2 + i) * 1024 + cx1);
    }
    if (pf) STAGE_B23(s2, k + 2);
    BAR();
    WAIT_LGKM0();
    __builtin_amdgcn_s_setprio(1);
#pragma unroll
    for (int i = 0; i < 2; ++i)
#pragma unroll
      for (int j = 0; j < 2; ++j) {
        acc[2 + i][2 + j] = __builtin_amdgcn_mfma_f32_16x16x32_bf16(a2[i][0], b2[j][0], acc[2 + i][2 + j], 0, 0, 0);
        acc[2 + i][2 + j] = __builtin_amdgcn_mfma_f32_16x16x32_bf16(a2[i][1], b2[j][1], acc[2 + i][2 + j], 0, 0, 0);
      }
    __builtin_amdgcn_s_setprio(0);

    // ---- Ph3: gate (counted) | BAR | MFMA q10 (regs only) -----------------
    if (pf) {
      WAIT_VM(6);   // tile k+1 fully landed; this tile's 6 stay in flight
    } else {
      WAIT_VM(0);   // tail drain
    }
    BAR();
    __builtin_amdgcn_s_setprio(1);
#pragma unroll
    for (int i = 0; i < 2; ++i)
#pragma unroll
      for (int j = 0; j < 2; ++j) {
        acc[2 + i][j] = __builtin_amdgcn_mfma_f32_16x16x32_bf16(a2[i][0], b0[j][0], acc[2 + i][j], 0, 0, 0);
        acc[2 + i][j] = __builtin_amdgcn_mfma_f32_16x16x32_bf16(a2[i][1], b0[j][1], acc[2 + i][j], 0, 0, 0);
      }
    __builtin_amdgcn_s_setprio(0);

    cur = (cur + 1 >= 3) ? 0 : cur + 1;
  }

  // epilogue: C/D layout col = l16, row = quad*4 + r ; relu -> bf16.
  // j-innermost so the 4 stores sharing a 64B line are adjacent in time.
  const long rowbase = (long)bm * 128 + wr * 64 + quad * 4;
  const int  colbase = bn * 256 + wc * 64 + l16;
  float bv[4];
#pragma unroll
  for (int j = 0; j < 4; ++j) bv[j] = bias[colbase + j * 16];
#pragma unroll
  for (int i = 0; i < 4; ++i) {
#pragma unroll
    for (int r = 0; r < 4; ++r) {
      const long row = rowbase + i * 16 + r;
#pragma unroll
      for (int j = 0; j < 4; ++j) {
        float v = acc[i][j][r] + bv[j];
        v = v > 0.0f ? v : 0.0f;
        C[row * DFF_DIM + colbase + j * 16] = f2bf(v);
      }
    }
  }
}

// ---------------------------------------------------------------------------
// GEMM2: round-0 PROVEN kernel, verbatim (111.4 us, twice-measured).
// 128x128 tile, BK=32, double-buffered LDS, chunk-XOR-4 swizzle.
// ---------------------------------------------------------------------------
template <int MODE>
__global__ __launch_bounds__(256)
void gemm_bt(const ushort_t* __restrict__ A, const ushort_t* __restrict__ Bt,
             const float* __restrict__ bias, void* __restrict__ Cv,
             int M, int N, int K) {
  __shared__ ushort_t As[2][128 * 32];
  __shared__ ushort_t Bs[2][128 * 32];

  const int tid  = threadIdx.x;
  const int lane = tid & 63;
  const int wave = tid >> 6;
  const int l16  = lane & 15;
  const int quad = lane >> 4;

  const int bm = blockIdx.x;
  const int bn = blockIdx.y;

  const int wm = (wave & 1) * 64;
  const int wn = (wave >> 1) * 64;

  const int swz  = (l16 & 3) ^ ((l16 >> 2) & 3);
  const int coff = (quad ^ swz) * 8;

  floatx4 acc[4][4];
#pragma unroll
  for (int i = 0; i < 4; ++i)
#pragma unroll
    for (int j = 0; j < 4; ++j)
      acc[i][j] = (floatx4)0.0f;

  const int s0 = tid, s1 = tid + 256;
  const int r0 = s0 >> 2, r1 = s1 >> 2;
  const int c0 = (s0 & 3) ^ (r0 & 3) ^ ((r0 >> 2) & 3);
  const int c1 = (s1 & 3) ^ (r1 & 3) ^ ((r1 >> 2) & 3);
  const ushort_t* gA0 = A + (long)(bm * 128 + r0) * K + c0 * 8;
  const ushort_t* gA1 = A + (long)(bm * 128 + r1) * K + c1 * 8;
  const ushort_t* gB0 = Bt + (long)(bn * 128 + r0) * K + c0 * 8;
  const ushort_t* gB1 = Bt + (long)(bn * 128 + r1) * K + c1 * 8;

  const int nk = K >> 5;

  load_lds16(gA0, &As[0][0] + s0 * 8);
  load_lds16(gA1, &As[0][0] + s1 * 8);
  load_lds16(gB0, &Bs[0][0] + s0 * 8);
  load_lds16(gB1, &Bs[0][0] + s1 * 8);

  for (int k = 0; k < nk; ++k) {
    const int cur = k & 1;
    const int nxt = cur ^ 1;
    __syncthreads();

    if (k + 1 < nk) {
      const int off = (k + 1) * 32;
      load_lds16(gA0 + off, &As[nxt][0] + s0 * 8);
      load_lds16(gA1 + off, &As[nxt][0] + s1 * 8);
      load_lds16(gB0 + off, &Bs[nxt][0] + s0 * 8);
      load_lds16(gB1 + off, &Bs[nxt][0] + s1 * 8);
    }

    short8 af[4], bf[4];
#pragma unroll
    for (int i = 0; i < 4; ++i)
      af[i] = *(const short8*)(&As[cur][0] + (wm + i * 16 + l16) * 32 + coff);
#pragma unroll
    for (int j = 0; j < 4; ++j)
      bf[j] = *(const short8*)(&Bs[cur][0] + (wn + j * 16 + l16) * 32 + coff);
#pragma unroll
    for (int i = 0; i < 4; ++i)
#pragma unroll
      for (int j = 0; j < 4; ++j)
        acc[i][j] = __builtin_amdgcn_mfma_f32_16x16x32_bf16(af[i], bf[j], acc[i][j], 0, 0, 0);
  }

#pragma unroll
  for (int i = 0; i < 4; ++i) {
#pragma unroll
    for (int j = 0; j < 4; ++j) {
      const int col = bn * 128 + wn + j * 16 + l16;
      const float bv = bias[col];
      const int row0 = bm * 128 + wm + i * 16 + quad * 4;
#pragma unroll
      for (int r = 0; r < 4; ++r) {
        float v = acc[i][j][r] + bv;
        if (MODE == 0) {
          v = v > 0.0f ? v : 0.0f;
          ((ushort_t*)Cv)[(long)(row0 + r) * N + col] = f2bf(v);
        } else {
          ((float*)Cv)[(long)(row0 + r) * N + col] = v;
        }
      }
    }
  }
}

extern "C" void kernel_launch(void* const* d_in, const int* in_sizes, int n_in,
                              void* d_out, int out_size, void* d_ws, size_t ws_size,
                              hipStream_t stream) {
  const float* h        = (const float*)d_in[0];
  const int*   span_idx = (const int*)d_in[1];
  const float* W1       = (const float*)d_in[2];
  const float* b1       = (const float*)d_in[3];
  const float* W2       = (const float*)d_in[4];
  const float* b2       = (const float*)d_in[5];
  float* out = (float*)d_out;

  // workspace layout (bf16 elements): A | W1T | W2T | Hmid
  ushort_t* A   = (ushort_t*)d_ws;
  ushort_t* W1T = A + (size_t)M_DIM * D_DIM;
  ushort_t* W2T = W1T + (size_t)DFF_DIM * D_DIM;
  ushort_t* Hm  = W2T + (size_t)D_DIM * DFF_DIM;

  // prep: W1 transpose + span gather (W2 transpose folded into gemm1 launch)
  prep<<<2304 + M_DIM / 4, 256, 0, stream>>>(W1, W1T, h, span_idx, A);

  // GEMM1 (+fused W2 transpose in tail blocks): 1536 GEMM + 288 transpose
  gemm1_p3<<<1536 + 288, 512, 0, stream>>>(A, W1T, b1, Hm, W2, W2T);

  // GEMM2: Hmid (M x DFF) * W2 (DFF x D) + b2 -> out fp32 (M x D)  [R0-proven]
  gemm_bt<1><<<dim3(M_DIM / 128, D_DIM / 128), 256, 0, stream>>>(
      Hm, W2T, b2, out, M_DIM, D_DIM, DFF_DIM);
}

// Round 11
// 272.784 us; speedup vs baseline: 1.0189x; 1.0189x over previous
//
#include <hip/hip_runtime.h>
#include <stdint.h>

#define B_DIM 4
#define L_DIM 512
#define D_DIM 768
#define S_DIM 4096
#define DFF_DIM 3072
#define M_DIM (B_DIM * S_DIM)   // 16384

typedef unsigned short ushort_t;
typedef __attribute__((ext_vector_type(8))) short short8;
typedef __attribute__((ext_vector_type(4))) short short4v;
typedef __attribute__((ext_vector_type(4))) float floatx4;

// round-to-nearest-even fp32 -> bf16 bits
__device__ __forceinline__ ushort_t f2bf(float x) {
  unsigned int u = __float_as_uint(x);
  u += 0x7FFFu + ((u >> 16) & 1u);
  return (ushort_t)(u >> 16);
}

// async 16B global->LDS (lane-contiguous dest)
__device__ __forceinline__ void load_lds16(const ushort_t* g, ushort_t* lds) {
  __builtin_amdgcn_global_load_lds(
      (const __attribute__((address_space(1))) unsigned int*)g,
      (__attribute__((address_space(3))) unsigned int*)lds, 16, 0, 0);
}

// single-barrier phase fence (no memory clobber -> no compiler vmcnt drain)
#define PIN() __builtin_amdgcn_sched_barrier(0)
#define BAR()                                  \
  do {                                         \
    PIN();                                     \
    __builtin_amdgcn_s_barrier();              \
    PIN();                                     \
  } while (0)
#define WAIT_LGKM0()                           \
  do {                                         \
    asm volatile("s_waitcnt lgkmcnt(0)");      \
    PIN();                                     \
  } while (0)
#define WAIT_VM(n)                             \
  do {                                         \
    asm volatile("s_waitcnt vmcnt(" #n ")");   \
    PIN();                                     \
  } while (0)

// ---------------------------------------------------------------------------
// Fused prep (R5-exact, 275.1 us composition): W1 transpose | W2 transpose |
// span gather+mean (float4 loads, serial loop).
// ---------------------------------------------------------------------------
__device__ __forceinline__ void transpose_body(const float* __restrict__ in,
                                               ushort_t* __restrict__ out,
                                               int K, int N, int kb, int nb) {
  __shared__ float tile[32][33];
  const int k0 = kb * 32;
  const int n0 = nb * 32;
  const int tx = threadIdx.x & 31;
  const int ty = threadIdx.x >> 5;  // 0..7
#pragma unroll
  for (int r = 0; r < 32; r += 8)
    tile[ty + r][tx] = in[(long)(k0 + ty + r) * N + n0 + tx];
  __syncthreads();
#pragma unroll
  for (int r = 0; r < 32; r += 8)
    out[(long)(n0 + ty + r) * K + k0 + tx] = f2bf(tile[tx][ty + r]);
}

__device__ __forceinline__ void span_body(const float* __restrict__ h,
                                          const int* __restrict__ span_idx,
                                          ushort_t* __restrict__ A, int blk) {
  const int wave = threadIdx.x >> 6;
  const int lane = threadIdx.x & 63;
  const int span = blk * 4 + wave;  // 0..M-1
  const int b = span >> 12;
  const int start = span_idx[span * 2 + 0];
  const int end   = span_idx[span * 2 + 1];
  const float inv = 1.0f / (float)(end - start + 1);
  const floatx4* hb =
      (const floatx4*)(h + ((long)b * L_DIM + start) * D_DIM) + lane;
  floatx4 a[3];
#pragma unroll
  for (int c = 0; c < 3; ++c) a[c] = (floatx4)0.0f;
  for (int p = start; p <= end; ++p) {
#pragma unroll
    for (int c = 0; c < 3; ++c) a[c] += hb[c * 64];
    hb += 192;
  }
  short4v* o = (short4v*)(A + (long)span * D_DIM) + lane;
#pragma unroll
  for (int c = 0; c < 3; ++c) {
    short4v s;
#pragma unroll
    for (int e = 0; e < 4; ++e) s[e] = (short)f2bf(a[c][e] * inv);
    o[c * 64] = s;
  }
}

__global__ __launch_bounds__(256)
void prep(const float* __restrict__ W1, ushort_t* __restrict__ W1T,
          const float* __restrict__ W2, ushort_t* __restrict__ W2T,
          const float* __restrict__ h, const int* __restrict__ span_idx,
          ushort_t* __restrict__ A) {
  const int blk = blockIdx.x;
  if (blk < 2304) {
    transpose_body(W1, W1T, D_DIM, DFF_DIM, blk % 24, blk / 24);
  } else if (blk < 4608) {
    const int b = blk - 2304;
    transpose_body(W2, W2T, DFF_DIM, D_DIM, b % 96, b / 96);
  } else {
    span_body(h, span_idx, A, blk - 4608);
  }
}

// ---------------------------------------------------------------------------
// GEMM1 (R5-proven K-loop, 102-105 us): single-barrier, triple-buffered,
// 128x256 BK=64. Epilogue: j-innermost store order (R10-proven: WRITE_SIZE
// 137 -> 103 MB via L2 write combining).
// ---------------------------------------------------------------------------
__global__ __launch_bounds__(512, 2)
void gemm1_p3(const ushort_t* __restrict__ A, const ushort_t* __restrict__ Bt,
              const float* __restrict__ bias, ushort_t* __restrict__ C) {
  __shared__ ushort_t As[3][128 * 64];  // 49152 B
  __shared__ ushort_t Bs[3][256 * 64];  // 98304 B

  const int tid  = threadIdx.x;
  const int lane = tid & 63;
  const int l16  = lane & 15;
  const int quad = lane >> 4;
  const int wave = tid >> 6;
  const int wr   = wave >> 2;  // 0..1 (M half, 64 rows)
  const int wc   = wave & 3;   // 0..3 (N quarter, 64 cols)

  const int bm = blockIdx.x;   // 0..127
  const int bn = blockIdx.y;   // 0..11

  // staging: seg s -> LDS row s>>3, slot s&7; global chunk = slot ^ (row&7)
  const int srow = tid >> 3;   // 0..63
  const int gch  = (tid & 7) ^ (srow & 7);
  const ushort_t* gA = A  + (long)(bm * 128 + srow) * 768 + gch * 8;
  const ushort_t* gB = Bt + (long)(bn * 256 + srow) * 768 + gch * 8;
  const long r64 = (long)768 * 64;  // 64-row stride (XOR pattern repeats mod 8)

  auto STAGE_A = [&](int buf, int kt) {   // A rows 0..127 (2 loads)
    const long ko = (long)kt * 64;
    ushort_t* la = &As[buf][0] + tid * 8;
    load_lds16(gA + ko,       la);
    load_lds16(gA + ko + r64, la + 4096);
  };
  auto STAGE_B01 = [&](int buf, int kt) { // B rows 0..127
    const long ko = (long)kt * 64;
    ushort_t* lb = &Bs[buf][0] + tid * 8;
    load_lds16(gB + ko,       lb);
    load_lds16(gB + ko + r64, lb + 4096);
  };
  auto STAGE_B23 = [&](int buf, int kt) { // B rows 128..255
    const long ko = (long)kt * 64;
    ushort_t* lb = &Bs[buf][0] + tid * 8;
    load_lds16(gB + ko + 2 * r64, lb + 8192);
    load_lds16(gB + ko + 3 * r64, lb + 12288);
  };

  // fragment reads: elem = row*64 + (kchunk ^ (row&7))*8 ; row&7 == l16&7
  const int arow0 = (wr * 64 + l16) * 64;
  const int brow0 = (wc * 64 + l16) * 64;
  const int cx0 = ((quad)     ^ (l16 & 7)) << 3;  // kstep 0
  const int cx1 = ((quad + 4) ^ (l16 & 7)) << 3;  // kstep 1

  floatx4 acc[4][4];
#pragma unroll
  for (int i = 0; i < 4; ++i)
#pragma unroll
    for (int j = 0; j < 4; ++j) acc[i][j] = (floatx4)0.0f;

  const int nk = 12;  // 768 / 64

  // prologue: stage tiles 0 and 1; gate tile 0 (tile 1's 6 stay in flight)
  STAGE_A(0, 0); STAGE_B01(0, 0); STAGE_B23(0, 0);
  STAGE_A(1, 1); STAGE_B01(1, 1); STAGE_B23(1, 1);
  WAIT_VM(6);
  BAR();

  short8 a0[2][2], a2[2][2], b0[2][2], b2[2][2];  // [frag][kstep]
  int cur = 0;

  for (int k = 0; k < nk; ++k) {
    const int s2 = (cur + 2 >= 3) ? cur - 1 : cur + 2;  // (k+2)%3
    const ushort_t* Ac = &As[cur][0];
    const ushort_t* Bc = &Bs[cur][0];
    const bool pf = (k + 2 < nk);

    // ---- Ph0: ds a0(i=0,1) + b0(j=0,1); stage A(k+2) | MFMA q00 ----------
#pragma unroll
    for (int i = 0; i < 2; ++i) {
      a0[i][0] = *(const short8*)(Ac + arow0 + i * 1024 + cx0);
      a0[i][1] = *(const short8*)(Ac + arow0 + i * 1024 + cx1);
    }
#pragma unroll
    for (int j = 0; j < 2; ++j) {
      b0[j][0] = *(const short8*)(Bc + brow0 + j * 1024 + cx0);
      b0[j][1] = *(const short8*)(Bc + brow0 + j * 1024 + cx1);
    }
    if (pf) STAGE_A(s2, k + 2);
    BAR();
    WAIT_LGKM0();
    __builtin_amdgcn_s_setprio(1);
#pragma unroll
    for (int i = 0; i < 2; ++i)
#pragma unroll
      for (int j = 0; j < 2; ++j) {
        acc[i][j] = __builtin_amdgcn_mfma_f32_16x16x32_bf16(a0[i][0], b0[j][0], acc[i][j], 0, 0, 0);
        acc[i][j] = __builtin_amdgcn_mfma_f32_16x16x32_bf16(a0[i][1], b0[j][1], acc[i][j], 0, 0, 0);
      }
    __builtin_amdgcn_s_setprio(0);

    // ---- Ph1: ds b2(j=2,3); stage B01(k+2) | MFMA q01 ---------------------
#pragma unroll
    for (int j = 0; j < 2; ++j) {
      b2[j][0] = *(const short8*)(Bc + brow0 + (2 + j) * 1024 + cx0);
      b2[j][1] = *(const short8*)(Bc + brow0 + (2 + j) * 1024 + cx1);
    }
    if (pf) STAGE_B01(s2, k + 2);
    BAR();
    WAIT_LGKM0();
    __builtin_amdgcn_s_setprio(1);
#pragma unroll
    for (int i = 0; i < 2; ++i)
#pragma unroll
      for (int j = 0; j < 2; ++j) {
        acc[i][2 + j] = __builtin_amdgcn_mfma_f32_16x16x32_bf16(a0[i][0], b2[j][0], acc[i][2 + j], 0, 0, 0);
        acc[i][2 + j] = __builtin_amdgcn_mfma_f32_16x16x32_bf16(a0[i][1], b2[j][1], acc[i][2 + j], 0, 0, 0);
      }
    __builtin_amdgcn_s_setprio(0);

    // ---- Ph2: ds a2(i=2,3); stage B23(k+2) | MFMA q11 ---------------------
#pragma unroll
    for (int i = 0; i < 2; ++i) {
      a2[i][0] = *(const short8*)(Ac + arow0 + (2 + i) * 1024 + cx0);
      a2[i][1] = *(const short8*)(Ac + arow0 + (2 + i) * 1024 + cx1);
    }
    if (pf) STAGE_B23(s2, k + 2);
    BAR();
    WAIT_LGKM0();
    __builtin_amdgcn_s_setprio(1);
#pragma unroll
    for (int i = 0; i < 2; ++i)
#pragma unroll
      for (int j = 0; j < 2; ++j) {
        acc[2 + i][2 + j] = __builtin_amdgcn_mfma_f32_16x16x32_bf16(a2[i][0], b2[j][0], acc[2 + i][2 + j], 0, 0, 0);
        acc[2 + i][2 + j] = __builtin_amdgcn_mfma_f32_16x16x32_bf16(a2[i][1], b2[j][1], acc[2 + i][2 + j], 0, 0, 0);
      }
    __builtin_amdgcn_s_setprio(0);

    // ---- Ph3: gate (counted) | BAR | MFMA q10 (regs only) -----------------
    if (pf) {
      WAIT_VM(6);   // tile k+1 fully landed; this tile's 6 stay in flight
    } else {
      WAIT_VM(0);   // tail drain
    }
    BAR();
    __builtin_amdgcn_s_setprio(1);
#pragma unroll
    for (int i = 0; i < 2; ++i)
#pragma unroll
      for (int j = 0; j < 2; ++j) {
        acc[2 + i][j] = __builtin_amdgcn_mfma_f32_16x16x32_bf16(a2[i][0], b0[j][0], acc[2 + i][j], 0, 0, 0);
        acc[2 + i][j] = __builtin_amdgcn_mfma_f32_16x16x32_bf16(a2[i][1], b0[j][1], acc[2 + i][j], 0, 0, 0);
      }
    __builtin_amdgcn_s_setprio(0);

    cur = (cur + 1 >= 3) ? 0 : cur + 1;
  }

  // epilogue: C/D layout col = l16, row = quad*4 + r ; relu -> bf16.
  // j-innermost: 4 stores sharing a 64B line are temporally adjacent
  // (R10-proven: WRITE_SIZE 137 -> 103 MB).
  const long rowbase = (long)bm * 128 + wr * 64 + quad * 4;
  const int  colbase = bn * 256 + wc * 64 + l16;
  float bv[4];
#pragma unroll
  for (int j = 0; j < 4; ++j) bv[j] = bias[colbase + j * 16];
#pragma unroll
  for (int i = 0; i < 4; ++i) {
#pragma unroll
    for (int r = 0; r < 4; ++r) {
      const long row = rowbase + i * 16 + r;
#pragma unroll
      for (int j = 0; j < 4; ++j) {
        float v = acc[i][j][r] + bv[j];
        v = v > 0.0f ? v : 0.0f;
        C[row * DFF_DIM + colbase + j * 16] = f2bf(v);
      }
    }
  }
}

// ---------------------------------------------------------------------------
// GEMM2: round-0 PROVEN kernel, verbatim (111.4 us, thrice-measured).
// 128x128 tile, BK=32, double-buffered LDS, chunk-XOR-4 swizzle.
// ---------------------------------------------------------------------------
template <int MODE>
__global__ __launch_bounds__(256)
void gemm_bt(const ushort_t* __restrict__ A, const ushort_t* __restrict__ Bt,
             const float* __restrict__ bias, void* __restrict__ Cv,
             int M, int N, int K) {
  __shared__ ushort_t As[2][128 * 32];
  __shared__ ushort_t Bs[2][128 * 32];

  const int tid  = threadIdx.x;
  const int lane = tid & 63;
  const int wave = tid >> 6;
  const int l16  = lane & 15;
  const int quad = lane >> 4;

  const int bm = blockIdx.x;
  const int bn = blockIdx.y;

  const int wm = (wave & 1) * 64;
  const int wn = (wave >> 1) * 64;

  const int swz  = (l16 & 3) ^ ((l16 >> 2) & 3);
  const int coff = (quad ^ swz) * 8;

  floatx4 acc[4][4];
#pragma unroll
  for (int i = 0; i < 4; ++i)
#pragma unroll
    for (int j = 0; j < 4; ++j)
      acc[i][j] = (floatx4)0.0f;

  const int s0 = tid, s1 = tid + 256;
  const int r0 = s0 >> 2, r1 = s1 >> 2;
  const int c0 = (s0 & 3) ^ (r0 & 3) ^ ((r0 >> 2) & 3);
  const int c1 = (s1 & 3) ^ (r1 & 3) ^ ((r1 >> 2) & 3);
  const ushort_t* gA0 = A + (long)(bm * 128 + r0) * K + c0 * 8;
  const ushort_t* gA1 = A + (long)(bm * 128 + r1) * K + c1 * 8;
  const ushort_t* gB0 = Bt + (long)(bn * 128 + r0) * K + c0 * 8;
  const ushort_t* gB1 = Bt + (long)(bn * 128 + r1) * K + c1 * 8;

  const int nk = K >> 5;

  load_lds16(gA0, &As[0][0] + s0 * 8);
  load_lds16(gA1, &As[0][0] + s1 * 8);
  load_lds16(gB0, &Bs[0][0] + s0 * 8);
  load_lds16(gB1, &Bs[0][0] + s1 * 8);

  for (int k = 0; k < nk; ++k) {
    const int cur = k & 1;
    const int nxt = cur ^ 1;
    __syncthreads();

    if (k + 1 < nk) {
      const int off = (k + 1) * 32;
      load_lds16(gA0 + off, &As[nxt][0] + s0 * 8);
      load_lds16(gA1 + off, &As[nxt][0] + s1 * 8);
      load_lds16(gB0 + off, &Bs[nxt][0] + s0 * 8);
      load_lds16(gB1 + off, &Bs[nxt][0] + s1 * 8);
    }

    short8 af[4], bf[4];
#pragma unroll
    for (int i = 0; i < 4; ++i)
      af[i] = *(const short8*)(&As[cur][0] + (wm + i * 16 + l16) * 32 + coff);
#pragma unroll
    for (int j = 0; j < 4; ++j)
      bf[j] = *(const short8*)(&Bs[cur][0] + (wn + j * 16 + l16) * 32 + coff);
#pragma unroll
    for (int i = 0; i < 4; ++i)
#pragma unroll
      for (int j = 0; j < 4; ++j)
        acc[i][j] = __builtin_amdgcn_mfma_f32_16x16x32_bf16(af[i], bf[j], acc[i][j], 0, 0, 0);
  }

#pragma unroll
  for (int i = 0; i < 4; ++i) {
#pragma unroll
    for (int j = 0; j < 4; ++j) {
      const int col = bn * 128 + wn + j * 16 + l16;
      const float bv = bias[col];
      const int row0 = bm * 128 + wm + i * 16 + quad * 4;
#pragma unroll
      for (int r = 0; r < 4; ++r) {
        float v = acc[i][j][r] + bv;
        if (MODE == 0) {
          v = v > 0.0f ? v : 0.0f;
          ((ushort_t*)Cv)[(long)(row0 + r) * N + col] = f2bf(v);
        } else {
          ((float*)Cv)[(long)(row0 + r) * N + col] = v;
        }
      }
    }
  }
}

extern "C" void kernel_launch(void* const* d_in, const int* in_sizes, int n_in,
                              void* d_out, int out_size, void* d_ws, size_t ws_size,
                              hipStream_t stream) {
  const float* h        = (const float*)d_in[0];
  const int*   span_idx = (const int*)d_in[1];
  const float* W1       = (const float*)d_in[2];
  const float* b1       = (const float*)d_in[3];
  const float* W2       = (const float*)d_in[4];
  const float* b2       = (const float*)d_in[5];
  float* out = (float*)d_out;

  // workspace layout (bf16 elements): A | W1T | W2T | Hmid
  ushort_t* A   = (ushort_t*)d_ws;
  ushort_t* W1T = A + (size_t)M_DIM * D_DIM;
  ushort_t* W2T = W1T + (size_t)DFF_DIM * D_DIM;
  ushort_t* Hm  = W2T + (size_t)D_DIM * DFF_DIM;

  // fused prep: both weight transposes + span gather (R5-exact)
  prep<<<2304 + 2304 + M_DIM / 4, 256, 0, stream>>>(W1, W1T, W2, W2T, h, span_idx, A);

  // GEMM1: single-barrier triple-buffer pipeline + j-innermost epilogue
  gemm1_p3<<<dim3(M_DIM / 128, DFF_DIM / 256), 512, 0, stream>>>(A, W1T, b1, Hm);

  // GEMM2: Hmid (M x DFF) * W2 (DFF x D) + b2 -> out fp32 (M x D)  [R0-proven]
  gemm_bt<1><<<dim3(M_DIM / 128, D_DIM / 128), 256, 0, stream>>>(
      Hm, W2T, b2, out, M_DIM, D_DIM, DFF_DIM);
}